// Round 3
// baseline (52.818 us; speedup 1.0000x reference)
//
#include <hip/hip_runtime.h>

#define NN 8192

// GLIF scalar constants
#define F_V_C          0.15f
#define DELTA_V_C      12.0f

typedef float v4f __attribute__((ext_vector_type(4)));

__global__ __launch_bounds__(256) void glif_kernel(
    const float* __restrict__ x_in,
    const float* __restrict__ w,
    const float* __restrict__ I_add,
    const float* __restrict__ v,
    const float* __restrict__ theta_s,
    const float* __restrict__ theta_v,
    const float* __restrict__ tau_m,
    const float* __restrict__ R_I,
    const float* __restrict__ v_rest,
    float* __restrict__ out)
{
    const int wid  = threadIdx.x >> 6;      // wave id within block (0..3)
    const int lane = threadIdx.x & 63;      // lane within 64-wide wave
    const int row0 = blockIdx.x * 8 + wid * 2;  // each wave owns 2 adjacent rows
    const int row1 = row0 + 1;

    const v4f* __restrict__ wrow0 =
        reinterpret_cast<const v4f*>(w + (size_t)row0 * NN);
    const v4f* __restrict__ wrow1 =
        reinterpret_cast<const v4f*>(w + (size_t)row1 * NN);
    const v4f* __restrict__ ia4 = reinterpret_cast<const v4f*>(I_add);

    float sum0 = 0.0f, sum1 = 0.0f;
    // 2048 float4s per row; 64 lanes -> 32 iters/lane; 3 loads + 8 fma per iter
    #pragma unroll 4
    for (int i = lane; i < NN / 4; i += 64) {
        v4f w0 = wrow0[i];
        v4f w1 = wrow1[i];
        v4f xv = ia4[i];
        sum0 = fmaf(w0.x, xv.x, sum0);
        sum0 = fmaf(w0.y, xv.y, sum0);
        sum0 = fmaf(w0.z, xv.z, sum0);
        sum0 = fmaf(w0.w, xv.w, sum0);
        sum1 = fmaf(w1.x, xv.x, sum1);
        sum1 = fmaf(w1.y, xv.y, sum1);
        sum1 = fmaf(w1.z, xv.z, sum1);
        sum1 = fmaf(w1.w, xv.w, sum1);
    }

    // 64-lane wave reduction (both rows)
    #pragma unroll
    for (int off = 32; off > 0; off >>= 1) {
        sum0 += __shfl_down(sum0, off, 64);
        sum1 += __shfl_down(sum1, off, 64);
    }

    if (lane == 0) {
        #pragma unroll
        for (int r = 0; r < 2; ++r) {
            const int   row = row0 + r;
            const float s   = (r == 0) ? sum0 : sum1;
            const float vr = v_rest[row];
            const float vv = v[row];
            const float I  = x_in[row] + s;
            const float v_next = vv + (vr - vv + I * R_I[row]) / tau_m[row];
            const float thresh = theta_s[row] + theta_v[row];
            const float d = v_next - thresh;
            const float sig = 1.0f / (1.0f + expf(-d));
            const float v_reset = vr + F_V_C * (vv - vr) - DELTA_V_C;
            const float v_new = (v_next >= thresh) ? v_reset : v_next;
            out[row]      = v_new;
            out[NN + row] = sig;
        }
    }
}

extern "C" void kernel_launch(void* const* d_in, const int* in_sizes, int n_in,
                              void* d_out, int out_size, void* d_ws, size_t ws_size,
                              hipStream_t stream) {
    const float* x_in    = (const float*)d_in[0];
    const float* w       = (const float*)d_in[1];
    const float* I_add   = (const float*)d_in[2];
    const float* v       = (const float*)d_in[3];
    const float* theta_s = (const float*)d_in[4];
    const float* theta_v = (const float*)d_in[5];
    const float* tau_m   = (const float*)d_in[6];
    const float* R_I     = (const float*)d_in[7];
    const float* v_rest  = (const float*)d_in[8];
    float* out = (float*)d_out;

    dim3 grid(NN / 8);   // 4 waves/block, 2 rows/wave -> 8 rows/block
    dim3 block(256);
    glif_kernel<<<grid, block, 0, stream>>>(
        x_in, w, I_add, v, theta_s, theta_v, tau_m, R_I, v_rest, out);
}

// Round 4
// 42.812 us; speedup vs baseline: 1.2337x; 1.2337x over previous
//
#include <hip/hip_runtime.h>

#define NN 8192

// GLIF scalar constants
#define F_V_C          0.15f
#define DELTA_V_C      12.0f

__global__ __launch_bounds__(256) void glif_kernel(
    const float* __restrict__ x_in,
    const float* __restrict__ w,
    const float* __restrict__ I_add,
    const float* __restrict__ v,
    const float* __restrict__ theta_s,
    const float* __restrict__ theta_v,
    const float* __restrict__ tau_m,
    const float* __restrict__ R_I,
    const float* __restrict__ v_rest,
    float* __restrict__ out)
{
    const int wid  = threadIdx.x >> 6;     // wave id within block (0..3)
    const int lane = threadIdx.x & 63;     // lane within 64-wide wave
    const int row  = blockIdx.x * 4 + wid; // one wave per output row

    const float4* __restrict__ wrow =
        reinterpret_cast<const float4*>(w + (size_t)row * NN);
    const float4* __restrict__ ia4 =
        reinterpret_cast<const float4*>(I_add);

    float sum = 0.0f;
    // 8192 cols / 4 per float4 = 2048 float4s; 64 lanes -> 32 iters/lane
    #pragma unroll 8
    for (int i = lane; i < NN / 4; i += 64) {
        float4 wv = wrow[i];
        float4 xv = ia4[i];
        sum = fmaf(wv.x, xv.x, sum);
        sum = fmaf(wv.y, xv.y, sum);
        sum = fmaf(wv.z, xv.z, sum);
        sum = fmaf(wv.w, xv.w, sum);
    }

    // 64-lane wave reduction
    #pragma unroll
    for (int off = 32; off > 0; off >>= 1)
        sum += __shfl_down(sum, off, 64);

    if (lane == 0) {
        const float vr = v_rest[row];
        const float vv = v[row];
        const float I  = x_in[row] + sum;
        const float v_next = vv + (vr - vv + I * R_I[row]) / tau_m[row];
        const float thresh = theta_s[row] + theta_v[row];
        const float d = v_next - thresh;
        // sigmoid
        const float sig = 1.0f / (1.0f + expf(-d));
        const float v_reset = vr + F_V_C * (vv - vr) - DELTA_V_C;
        const float v_new = (v_next >= thresh) ? v_reset : v_next;
        out[row]      = v_new;
        out[NN + row] = sig;
    }
}

extern "C" void kernel_launch(void* const* d_in, const int* in_sizes, int n_in,
                              void* d_out, int out_size, void* d_ws, size_t ws_size,
                              hipStream_t stream) {
    const float* x_in    = (const float*)d_in[0];
    const float* w       = (const float*)d_in[1];
    const float* I_add   = (const float*)d_in[2];
    const float* v       = (const float*)d_in[3];
    const float* theta_s = (const float*)d_in[4];
    const float* theta_v = (const float*)d_in[5];
    const float* tau_m   = (const float*)d_in[6];
    const float* R_I     = (const float*)d_in[7];
    const float* v_rest  = (const float*)d_in[8];
    float* out = (float*)d_out;

    dim3 grid(NN / 4);   // 4 rows (waves) per block
    dim3 block(256);
    glif_kernel<<<grid, block, 0, stream>>>(
        x_in, w, I_add, v, theta_s, theta_v, tau_m, R_I, v_rest, out);
}